// Round 12
// baseline (568.423 us; speedup 1.0000x reference)
//
#include <hip/hip_runtime.h>
#include <hip/hip_bf16.h>

#define S_ 128
#define N_ 384
#define CM 256
#define CH 32
#define CZ 128

typedef __attribute__((ext_vector_type(8))) __bf16 bf16x8;
typedef __attribute__((ext_vector_type(4))) float f32x4;

union pack4 { __hip_bfloat16 h[4]; uint2 u; };

// ---- Kernel P: fused prep (wt12 + woutT + RN) — one launch ---------------
__global__ __launch_bounds__(384) void k_prep(const float* __restrict__ w1,
                                              const float* __restrict__ w2,
                                              const float* __restrict__ wout,
                                              const float* __restrict__ mask,
                                              __hip_bfloat16* __restrict__ wt12,
                                              __hip_bfloat16* __restrict__ woutT,
                                              float* __restrict__ RN)
{
    const int b = blockIdx.x, t = threadIdx.x;
    if (b < 64) {
        if (t < 256) {
            const float* w = (b < CH) ? w1 : w2;
            wt12[b * CM + t] = __float2bfloat16(w[(size_t)t * CH + (b & 31)]);
        }
    } else if (b < 192) {
        const int z = b - 64;
        for (int cd = t; cd < CH*CH; cd += 384)
            woutT[(size_t)z * (CH*CH) + cd] = __float2bfloat16(wout[(size_t)cd * CZ + z]);
    } else {
        const int i = b - 192, j = t;
        float acc = 0.f;
        #pragma unroll 8
        for (int s = 0; s < S_; ++s)
            acc += mask[s*N_ + i] * mask[s*N_ + j];
        RN[i*N_ + j] = 1.0f / (acc + 1e-3f);
    }
}

// ---- Kernel 1: LayerNorm + dual projection via MFMA (R11 champion) -------
#define LNR 264
__global__ __launch_bounds__(256) void k_lnp(
    const float* __restrict__ m, const float* __restrict__ mask,
    const float* __restrict__ gamma, const float* __restrict__ beta,
    const float* __restrict__ b1, const float* __restrict__ b2,
    const __hip_bfloat16* __restrict__ wt12,
    __hip_bfloat16* __restrict__ At, __hip_bfloat16* __restrict__ Bt)
{
    __shared__ __hip_bfloat16 lnS[128 * LNR];
    __shared__ float msk[128];
    const int n0 = blockIdx.x * 16, s0 = blockIdx.y * 8;
    const int t = threadIdx.x, wave = t >> 6, lane = t & 63;
    const int l15 = lane & 15, quad = lane >> 4;

    if (t < 128) msk[t] = mask[(s0 + (t & 7))*N_ + n0 + (t >> 3)];

    float4 ga[4], be4[4];
    #pragma unroll
    for (int u = 0; u < 4; ++u) {
        ga[u]  = ((const float4*)gamma)[u*16 + l15];
        be4[u] = ((const float4*)beta )[u*16 + l15];
    }

    for (int it = 0; it < 8; ++it) {
        const int row = wave*32 + it*4 + quad;
        const int n = row >> 3, s = row & 7;
        const float4* src = (const float4*)(m + ((size_t)((s0+s)*N_ + n0 + n)) * CM);
        float4 x[4];
        #pragma unroll
        for (int u = 0; u < 4; ++u) x[u] = src[u*16 + l15];

        float sum = 0.f, ssq = 0.f;
        #pragma unroll
        for (int u = 0; u < 4; ++u) {
            sum += x[u].x + x[u].y + x[u].z + x[u].w;
            ssq += x[u].x*x[u].x + x[u].y*x[u].y + x[u].z*x[u].z + x[u].w*x[u].w;
        }
        #pragma unroll
        for (int off = 8; off >= 1; off >>= 1) {
            sum += __shfl_xor(sum, off, 64);
            ssq += __shfl_xor(ssq, off, 64);
        }
        const float mean = sum * (1.0f/CM);
        const float var  = ssq * (1.0f/CM) - mean*mean;
        const float rstd = rsqrtf(var + 1e-5f);

        #pragma unroll
        for (int u = 0; u < 4; ++u) {
            pack4 pk;
            pk.h[0] = __float2bfloat16((x[u].x - mean)*rstd*ga[u].x + be4[u].x);
            pk.h[1] = __float2bfloat16((x[u].y - mean)*rstd*ga[u].y + be4[u].y);
            pk.h[2] = __float2bfloat16((x[u].z - mean)*rstd*ga[u].z + be4[u].z);
            pk.h[3] = __float2bfloat16((x[u].w - mean)*rstd*ga[u].w + be4[u].w);
            *(uint2*)&lnS[row*LNR + (u*16 + l15)*4] = pk.u;
        }
    }
    __syncthreads();

    f32x4 acc[2][4];
    const f32x4 z4 = {0.f,0.f,0.f,0.f};
    #pragma unroll
    for (int mt = 0; mt < 2; ++mt)
        #pragma unroll
        for (int nt = 0; nt < 4; ++nt) acc[mt][nt] = z4;

    #pragma unroll
    for (int kk = 0; kk < 8; ++kk) {
        bf16x8 a0 = *(const bf16x8*)&lnS[(wave*32      + l15)*LNR + kk*32 + quad*8];
        bf16x8 a1 = *(const bf16x8*)&lnS[(wave*32 + 16 + l15)*LNR + kk*32 + quad*8];
        #pragma unroll
        for (int nt = 0; nt < 4; ++nt) {
            bf16x8 wv = *(const bf16x8*)&wt12[(size_t)(nt*16 + l15)*CM + kk*32 + quad*8];
            acc[0][nt] = __builtin_amdgcn_mfma_f32_16x16x32_bf16(a0, wv, acc[0][nt], 0,0,0);
            acc[1][nt] = __builtin_amdgcn_mfma_f32_16x16x32_bf16(a1, wv, acc[1][nt], 0,0,0);
        }
    }

    #pragma unroll
    for (int nt = 0; nt < 4; ++nt) {
        const int ncol = nt*16 + l15;
        const int sel = ncol >> 5, c = ncol & 31;
        const float bias = sel ? b2[c] : b1[c];
        __hip_bfloat16* dst = sel ? Bt : At;
        #pragma unroll
        for (int mt = 0; mt < 2; ++mt) {
            const int rowb = wave*32 + mt*16 + quad*4;
            const int n_loc = rowb >> 3, s_loc = rowb & 7;
            pack4 pk;
            #pragma unroll
            for (int r = 0; r < 4; ++r)
                pk.h[r] = __float2bfloat16((acc[mt][nt][r] + bias) * msk[rowb + r]);
            *(uint2*)&dst[((size_t)(n0 + n_loc)*CH + c)*S_ + s0 + s_loc] = pk.u;
        }
    }
}

// ---- NEW Kernel 2a: k_outer — outer-product GEMM to global ---------------
// C[i*32+c][j*32+d] = sum_s At[i,c,s] Bt[j,d,s]: M=N=12288-equiv, K=128.
// Block 256 thr / 4 waves, tile 4i x 4j (128 x 128). Fragments go through a
// 37 KB LDS tile (c*36 padded, champion-verified layout) and are linearized
// to fully-coalesced 2 KB global stores -> no partial-line write
// amplification. Grid (CI/4, 96), bx = i fastest (j-band L2 residency).
#define ONR 1160
__global__ __launch_bounds__(256) void k_outer(
    const __hip_bfloat16* __restrict__ At, const __hip_bfloat16* __restrict__ Bt,
    __hip_bfloat16* __restrict__ Og, int i_base)
{
    __shared__ __hip_bfloat16 Ol[16 * ONR];   // 36.25 KB
    const int t = threadIdx.x;
    const int wave = t >> 6, lane = t & 63;
    const int l15 = lane & 15, quad = lane >> 4;
    const int mhalf = wave & 1, nhalf = wave >> 1;
    const int i0l = blockIdx.x * 4;           // local i (within chunk)
    const int i0 = i_base + i0l;              // absolute i
    const int j0 = blockIdx.y * 4;
    const f32x4 z4 = {0.f,0.f,0.f,0.f};

    f32x4 acc[4][4];                          // [nt][mt]
    #pragma unroll
    for (int nt = 0; nt < 4; ++nt)
        #pragma unroll
        for (int mt = 0; mt < 4; ++mt) acc[nt][mt] = z4;

    const __hip_bfloat16* Ag[4];
    #pragma unroll
    for (int mt = 0; mt < 4; ++mt) {
        const int Mrow = mhalf*64 + mt*16 + l15;      // = i_l*32 + c
        Ag[mt] = At + ((size_t)(i0 + (Mrow >> 5)) * CH + (Mrow & 31)) * S_ + quad*8;
    }
    const __hip_bfloat16* Bg[4];
    #pragma unroll
    for (int nt = 0; nt < 4; ++nt) {
        const int Ncol = nhalf*64 + nt*16 + l15;      // = j_l*32 + d
        Bg[nt] = Bt + ((size_t)(j0 + (Ncol >> 5)) * CH + (Ncol & 31)) * S_ + quad*8;
    }

    #pragma unroll
    for (int kk = 0; kk < 4; ++kk) {
        bf16x8 af[4], bfr[4];
        #pragma unroll
        for (int mt = 0; mt < 4; ++mt) af[mt]  = *(const bf16x8*)(Ag[mt] + kk*32);
        #pragma unroll
        for (int nt = 0; nt < 4; ++nt) bfr[nt] = *(const bf16x8*)(Bg[nt] + kk*32);
        #pragma unroll
        for (int nt = 0; nt < 4; ++nt)
            #pragma unroll
            for (int mt = 0; mt < 4; ++mt)
                acc[nt][mt] = __builtin_amdgcn_mfma_f32_16x16x32_bf16(
                    bfr[nt], af[mt], acc[nt][mt], 0, 0, 0);
    }

    // fragment -> LDS (verified champion OWRITE pattern, 16 p rows)
    #pragma unroll
    for (int mt = 0; mt < 4; ++mt) {
        const int Mcol = mhalf*64 + mt*16 + l15;
        const int i_l = Mcol >> 5, c = Mcol & 31;
        #pragma unroll
        for (int nt = 0; nt < 4; ++nt) {
            const int Nrow = nhalf*64 + nt*16 + quad*4;
            const int j_l = Nrow >> 5, d0 = Nrow & 31;
            const int p = i_l*4 + j_l;
            pack4 pk;
            #pragma unroll
            for (int r = 0; r < 4; ++r) pk.h[r] = __float2bfloat16(acc[nt][mt][r]);
            *(uint2*)&Ol[p*ONR + c*36 + d0] = pk.u;
        }
    }
    __syncthreads();

    // linearize: 16 pairs x 1024 cd -> Og[(i_loc*384 + j)][cd], 2 KB
    // contiguous per 128-thread group
    #pragma unroll
    for (int ps = 0; ps < 8; ++ps) {
        const int g  = ps*2048 + t*8;
        const int p  = g >> 10, cd = g & 1023;
        const int c  = cd >> 5, d = cd & 31;
        const int pi = p >> 2,  pj = p & 3;
        uint2 a0 = *(const uint2*)&Ol[p*ONR + c*36 + d];
        uint2 a1 = *(const uint2*)&Ol[p*ONR + c*36 + d + 4];
        uint4 v; v.x = a0.x; v.y = a0.y; v.z = a1.x; v.w = a1.y;
        *(uint4*)&Og[((size_t)(i0l + pi)*N_ + (j0 + pj))*1024 + cd] = v;
    }
}

// ---- NEW Kernel 2b: k_wo — [P x 1024] @ [1024 x 128] + bias, x RN --------
// Canonical streaming GEMM: Og staged global->LDS coalesced (8 x 4 KB
// passes), woutT (256 KB, L2) direct to regs. Block 256 thr / 4 waves,
// tile 128 p x 128 z, K = 1024 in 8 chunks of 128. LDS 33 KB.
__global__ __launch_bounds__(256) void k_wo(
    const __hip_bfloat16* __restrict__ Og, const __hip_bfloat16* __restrict__ woutT,
    const float* __restrict__ RN, const float* __restrict__ bout,
    float* __restrict__ out, int p_base)
{
    __shared__ __hip_bfloat16 As[128 * 132];   // 33 KB, pad 4
    const int t = threadIdx.x;
    const int wave = t >> 6, lane = t & 63;
    const int l15 = lane & 15, quad = lane >> 4;
    const int p0 = blockIdx.x * 128;           // local p
    const f32x4 z4 = {0.f,0.f,0.f,0.f};

    f32x4 acc[2][8];                           // [mt][nt]
    #pragma unroll
    for (int mt = 0; mt < 2; ++mt)
        #pragma unroll
        for (int nt = 0; nt < 8; ++nt) acc[mt][nt] = z4;

    for (int kc = 0; kc < 8; ++kc) {
        uint4 ld[8];
        #pragma unroll
        for (int ps = 0; ps < 8; ++ps) {
            const int idx = ps*256 + t;
            const int r = idx >> 4, colb = (idx & 15)*8;
            ld[ps] = *(const uint4*)&Og[((size_t)(p0 + r))*1024 + kc*128 + colb];
        }
        __syncthreads();                        // prev chunk's reads done
        #pragma unroll
        for (int ps = 0; ps < 8; ++ps) {
            const int idx = ps*256 + t;
            const int r = idx >> 4, colb = (idx & 15)*8;
            *(uint4*)&As[r*132 + colb] = ld[ps];
        }
        __syncthreads();

        #pragma unroll
        for (int kk = 0; kk < 4; ++kk) {
            bf16x8 a[2];
            #pragma unroll
            for (int mt = 0; mt < 2; ++mt)
                a[mt] = *(const bf16x8*)&As[(wave*32 + mt*16 + l15)*132 + kk*32 + quad*8];
            bf16x8 wf[8];
            #pragma unroll
            for (int nt = 0; nt < 8; ++nt)
                wf[nt] = *(const bf16x8*)&woutT[(size_t)(nt*16 + l15)*(CH*CH)
                                                + kc*128 + kk*32 + quad*8];
            #pragma unroll
            for (int mt = 0; mt < 2; ++mt)
                #pragma unroll
                for (int nt = 0; nt < 8; ++nt)
                    acc[mt][nt] = __builtin_amdgcn_mfma_f32_16x16x32_bf16(
                        a[mt], wf[nt], acc[mt][nt], 0, 0, 0);
        }
    }

    // epilogue: col(l15) -> z, row(quad,r) -> p  (champion-verified mapping)
    #pragma unroll
    for (int nt = 0; nt < 8; ++nt) {
        const int z = nt*16 + l15;
        const float bz = bout[z];
        #pragma unroll
        for (int mt = 0; mt < 2; ++mt) {
            #pragma unroll
            for (int r = 0; r < 4; ++r) {
                const int p_loc = p0 + wave*32 + mt*16 + quad*4 + r;
                const int pg = p_base + p_loc;
                out[(size_t)pg*CZ + z] = (acc[mt][nt][r] + bz) * RN[pg];
            }
        }
    }
}

// ---- FALLBACK Kernel 2: fused k_opm (R11 champion, verbatim) -------------
#define OR 1160
__global__ __launch_bounds__(512) void k_opm(
    const __hip_bfloat16* __restrict__ At, const __hip_bfloat16* __restrict__ Bt,
    const float* __restrict__ RN, const __hip_bfloat16* __restrict__ woutT,
    const float* __restrict__ bout, float* __restrict__ out)
{
    __shared__ __hip_bfloat16 O[64 * OR];
    const int t = threadIdx.x;
    const int wave = t >> 6, lane = t & 63;
    const int l15 = lane & 15, quad = lane >> 4;
    const int i0 = blockIdx.x * 8, j0 = blockIdx.y * 8;
    const int mhalf = wave & 1, nquad = wave >> 1;

    f32x4 acc[4][8];
    const f32x4 z4 = {0.f,0.f,0.f,0.f};
    #pragma unroll
    for (int nt = 0; nt < 4; ++nt)
        #pragma unroll
        for (int mt = 0; mt < 8; ++mt) acc[nt][mt] = z4;

    const __hip_bfloat16* Ag[8];
    #pragma unroll
    for (int mt = 0; mt < 8; ++mt) {
        const int Mrow = mhalf*128 + mt*16 + l15;
        Ag[mt] = At + ((size_t)(i0 + (Mrow >> 5)) * CH + (Mrow & 31)) * S_ + quad*8;
    }
    const __hip_bfloat16* Bg[4];
    #pragma unroll
    for (int nt = 0; nt < 4; ++nt) {
        const int Ncol = nquad*64 + nt*16 + l15;
        Bg[nt] = Bt + ((size_t)(j0 + (Ncol >> 5)) * CH + (Ncol & 31)) * S_ + quad*8;
    }

    #pragma unroll
    for (int kk = 0; kk < 4; ++kk) {
        bf16x8 af[8], bfr[4];
        #pragma unroll
        for (int mt = 0; mt < 8; ++mt) af[mt] = *(const bf16x8*)(Ag[mt] + kk*32);
        #pragma unroll
        for (int nt = 0; nt < 4; ++nt) bfr[nt] = *(const bf16x8*)(Bg[nt] + kk*32);
        #pragma unroll
        for (int nt = 0; nt < 4; ++nt)
            #pragma unroll
            for (int mt = 0; mt < 8; ++mt)
                acc[nt][mt] = __builtin_amdgcn_mfma_f32_16x16x32_bf16(
                    bfr[nt], af[mt], acc[nt][mt], 0, 0, 0);
    }

    #pragma unroll
    for (int mt = 0; mt < 8; ++mt) {
        const int Mcol = mhalf*128 + mt*16 + l15;
        const int i_l = Mcol >> 5, c = Mcol & 31;
        #pragma unroll
        for (int nt = 0; nt < 4; ++nt) {
            const int Nrow = nquad*64 + nt*16 + quad*4;
            const int j_l = Nrow >> 5, d0 = Nrow & 31;
            const int p = i_l*8 + j_l;
            pack4 pk;
            #pragma unroll
            for (int r = 0; r < 4; ++r) pk.h[r] = __float2bfloat16(acc[nt][mt][r]);
            *(uint2*)&O[p*OR + c*36 + d0] = pk.u;
        }
    }
    __syncthreads();

    const int zb = wave * 16;
    f32x4 oacc[4];
    #pragma unroll
    for (int mt = 0; mt < 4; ++mt) oacc[mt] = z4;

    #pragma unroll
    for (int h = 0; h < 2; ++h) {
        bf16x8 wf[16];
        #pragma unroll
        for (int k2 = 0; k2 < 16; ++k2)
            wf[k2] = *(const bf16x8*)&woutT[(size_t)(zb + l15) * (CH*CH)
                                            + (h*16 + k2)*32 + quad*8];
        #pragma unroll
        for (int k2 = 0; k2 < 16; ++k2) {
            const int kk = h*16 + k2;
            #pragma unroll
            for (int mt = 0; mt < 4; ++mt) {
                bf16x8 a = *(const bf16x8*)&O[(mt*16 + l15)*OR + kk*36 + quad*8];
                oacc[mt] = __builtin_amdgcn_mfma_f32_16x16x32_bf16(
                    a, wf[k2], oacc[mt], 0, 0, 0);
            }
        }
    }

    const int zc = zb + l15;
    const float bz = bout[zc];
    #pragma unroll
    for (int mt = 0; mt < 4; ++mt) {
        #pragma unroll
        for (int r = 0; r < 4; ++r) {
            const int p = mt*16 + quad*4 + r;
            const int i = i0 + (p >> 3), j = j0 + (p & 7);
            const float rn = RN[i*N_ + j];
            out[((size_t)(i*N_ + j))*CZ + zc] = (oacc[mt][r] + bz) * rn;
        }
    }
}

extern "C" void kernel_launch(void* const* d_in, const int* in_sizes, int n_in,
                              void* d_out, int out_size, void* d_ws, size_t ws_size,
                              hipStream_t stream)
{
    const float* m    = (const float*)d_in[0];
    const float* mask = (const float*)d_in[1];
    const float* gam  = (const float*)d_in[2];
    const float* bet  = (const float*)d_in[3];
    const float* w1   = (const float*)d_in[4];
    const float* b1   = (const float*)d_in[5];
    const float* w2   = (const float*)d_in[6];
    const float* b2   = (const float*)d_in[7];
    const float* wout = (const float*)d_in[8];
    const float* bout = (const float*)d_in[9];
    float* out = (float*)d_out;

    __hip_bfloat16* At    = (__hip_bfloat16*)d_ws;                 // [N][CH][S]
    __hip_bfloat16* Bt    = At + (size_t)N_ * CH * S_;             // [N][CH][S]
    __hip_bfloat16* woutT = Bt + (size_t)N_ * CH * S_;             // [CZ][1024]
    __hip_bfloat16* wt12  = woutT + (size_t)CZ * CH * CH;          // [64][256]
    float*          RN    = (float*)(wt12 + (size_t)64 * CM);      // [N][N]
    const size_t base = (size_t)N_*CH*S_*2*2 + (size_t)CZ*CH*CH*2
                      + (size_t)64*CM*2 + (size_t)N_*N_*4;         // 7,176,192 B

    k_prep<<<576, 384, 0, stream>>>(w1, w2, wout, mask, wt12, woutT, RN);
    dim3 gl(24, 16);
    k_lnp<<<gl, 256, 0, stream>>>(m, mask, gam, bet, b1, b2, wt12, At, Bt);

    // tiered Og chunking by available workspace; fallback = champion k_opm
    int CI = 0;
    const int cands[3] = {384, 192, 96};
    for (int c = 0; c < 3; ++c) {
        const size_t need = base + (size_t)cands[c] * N_ * 1024 * 2;
        if (need <= ws_size) { CI = cands[c]; break; }
    }

    if (CI) {
        __hip_bfloat16* Og = (__hip_bfloat16*)((char*)d_ws + base);
        const int nch = N_ / CI;
        for (int c = 0; c < nch; ++c) {
            dim3 go(CI/4, 96);
            k_outer<<<go, 256, 0, stream>>>(At, Bt, Og, c*CI);
            k_wo<<<CI*3, 256, 0, stream>>>(Og, woutT, RN, bout, out, c*CI*N_);
        }
    } else {
        dim3 grid(N_ / 8, N_ / 8);
        k_opm<<<grid, 512, 0, stream>>>(At, Bt, RN, woutT, bout, out);
    }
}